// Round 1
// 34699.390 us; speedup vs baseline: 1.0457x; 1.0457x over previous
//
#include <hip/hip_runtime.h>
#include <hip/hip_bf16.h>

// CustomRNNmodel: emb -> 2-layer LSTM -> LN -> tied LM head (V=32000,H=1024,L=2,B=4,T=1024)
//
// R1 change: the LSTM grid barrier was the bottleneck (17.2us/step, all in a 256-way
// single-cacheline atomic RMW + 256 spinners on the same line). Restructured:
//  - 32 blocks x 512 threads (8 waves/block, 2 waves/SIMD). Each wave owns 16 gate rows
//    (W_hh slice VGPR-resident as MFMA B-fragments, as before).
//  - Grid barrier = per-block flag array (256B stride, release store) + per-wave vectorized
//    acquire poll of all 32 flags (lane i polls flag i, __any reduce). No RMW contention.
//  - h broadcast buffer shrunk to 4 rows (batch); lanes n>=4 duplicate row n&3 (MFMA D rows
//    4..15 are discarded anyway).
//  - pre[t] gather prefetched into regs before the poll (in flight during the wait).
//
// All big GEMMs unchanged: C[M,N] = A[M,K=1024] . B[N,K]^T (bf16 MFMA 16x16x32, 128x128 tile,
// 4 waves x 4x4 tiles, fp32 accum). Verified fragment layouts:
//   A/B operand: elem[j] = M[row=lane&15][k=quad*8+j]; C/D: n=lane&15, m=quad*4+reg.

#define T_SEQ 1024

typedef __attribute__((ext_vector_type(8))) short bf16x8;
typedef __attribute__((ext_vector_type(4))) float f32x4;
typedef __attribute__((ext_vector_type(4))) int i32x4;

__device__ __forceinline__ unsigned short f2bf(float f) {
  union { float f; unsigned u; } v; v.f = f;
  unsigned r = v.u + 0x7fffu + ((v.u >> 16) & 1u);   // RNE
  return (unsigned short)(r >> 16);
}
__device__ __forceinline__ float bf2f(unsigned short s) {
  union { unsigned u; float f; } v; v.u = ((unsigned)s) << 16;
  return v.f;
}
__device__ __forceinline__ float sigm(float x) { return 1.f / (1.f + __expf(-x)); }
__device__ __forceinline__ float tanh_f(float x) {
  return 1.f - 2.f / (__expf(2.f * x) + 1.f);
}

// ---------------- fp32 -> bf16 bulk convert (4 elems/thread) ----------------
__global__ __launch_bounds__(256) void cvt_bf16(const float* __restrict__ src,
                                                unsigned short* __restrict__ dst, int n4) {
  int i = blockIdx.x * 256 + threadIdx.x;
  if (i >= n4) return;
  float4 f = ((const float4*)src)[i];
  ushort4 o;
  o.x = f2bf(f.x); o.y = f2bf(f.y); o.z = f2bf(f.z); o.w = f2bf(f.w);
  ((ushort4*)dst)[i] = o;
}

// ---------------- embedding: feats[b*T+t][h] = wemb[id][h] + pemb[t][h] ----------------
__global__ __launch_bounds__(256) void embed_k(const int* __restrict__ ids,
                                               const float* __restrict__ wemb,
                                               const float* __restrict__ pemb,
                                               unsigned short* __restrict__ out) {
  int i = blockIdx.x * 256 + threadIdx.x;     // 0 .. 4*1024*1024-1
  int h = i & 1023;
  int bt = i >> 10;
  int t = bt & (T_SEQ - 1);
  int id = ids[bt];
  out[i] = f2bf(wemb[(size_t)id * 1024 + h] + pemb[(size_t)t * 1024 + h]);
}

// ---------------- bf16 GEMM: C[M,N] = A[M,K=1024] . B[N,K=1024]^T, fp32 out ----------------
__global__ __launch_bounds__(256) void gemm_bt(const unsigned short* __restrict__ A,
                                               const unsigned short* __restrict__ B,
                                               float* __restrict__ C, int N) {
  const int K = 1024;
  __shared__ __align__(16) unsigned short lA[128 * 32];
  __shared__ __align__(16) unsigned short lB[128 * 32];
  int tid = threadIdx.x;
  int m0 = blockIdx.y * 128, n0 = blockIdx.x * 128;
  int wave = tid >> 6, lane = tid & 63;
  int wr = (wave >> 1) * 64, wc = (wave & 1) * 64;
  int lrow = lane & 15, quad = lane >> 4;
  f32x4 z = {0.f, 0.f, 0.f, 0.f};
  f32x4 acc[4][4];
  for (int i = 0; i < 4; ++i)
    for (int j = 0; j < 4; ++j) acc[i][j] = z;
  // staging: 512 16B chunks per tile; chunk c -> row c>>2, koff (c&3)*8; LDS row-major [128][32]
  int c0 = tid, c1 = tid + 256;
  const unsigned short* gA0 = A + (size_t)(m0 + (c0 >> 2)) * K + (c0 & 3) * 8;
  const unsigned short* gA1 = A + (size_t)(m0 + (c1 >> 2)) * K + (c1 & 3) * 8;
  const unsigned short* gB0 = B + (size_t)(n0 + (c0 >> 2)) * K + (c0 & 3) * 8;
  const unsigned short* gB1 = B + (size_t)(n0 + (c1 >> 2)) * K + (c1 & 3) * 8;
  unsigned short* sA0 = lA + c0 * 8;
  unsigned short* sA1 = lA + c1 * 8;
  unsigned short* sB0 = lB + c0 * 8;
  unsigned short* sB1 = lB + c1 * 8;
  for (int k0 = 0; k0 < K; k0 += 32) {
    __syncthreads();
    *(i32x4*)sA0 = *(const i32x4*)(gA0 + k0);
    *(i32x4*)sA1 = *(const i32x4*)(gA1 + k0);
    *(i32x4*)sB0 = *(const i32x4*)(gB0 + k0);
    *(i32x4*)sB1 = *(const i32x4*)(gB1 + k0);
    __syncthreads();
    bf16x8 a[4], b[4];
#pragma unroll
    for (int i = 0; i < 4; ++i)
      a[i] = *(const bf16x8*)(lA + (wr + i * 16 + lrow) * 32 + quad * 8);
#pragma unroll
    for (int j = 0; j < 4; ++j)
      b[j] = *(const bf16x8*)(lB + (wc + j * 16 + lrow) * 32 + quad * 8);
#pragma unroll
    for (int i = 0; i < 4; ++i)
#pragma unroll
      for (int j = 0; j < 4; ++j)
        acc[i][j] = __builtin_amdgcn_mfma_f32_16x16x32_bf16(a[i], b[j], acc[i][j], 0, 0, 0);
  }
  int crow = m0 + wr + quad * 4;
  int ccol = n0 + wc + lrow;
#pragma unroll
  for (int i = 0; i < 4; ++i)
#pragma unroll
    for (int j = 0; j < 4; ++j)
#pragma unroll
      for (int r = 0; r < 4; ++r)
        C[(size_t)(crow + i * 16 + r) * N + (ccol + j * 16)] = acc[i][j][r];
}

// ---------------- persistent LSTM layer ----------------
// 32 blocks x 512 threads (8 waves). Wave w of block blk owns hidden units
// u in [blk*32 + w*4, blk*32 + w*4 + 4): gate rows {g*1024 + u} for g in {i,f,g,o} -> 16 rows
// = one MFMA B-operand n-dim. W_hh slice pre-packed into 32 B-fragments (VGPR-resident).
// h state: global bf16 [2(ping-pong)][4][1024]; row = batch.
// Grid barrier: per-block flag (stride 64 u32 = 256B) release-stored with step count;
// every wave polls all 32 flags (lane&31 -> flag) with agent-scope acquire loads.
__global__ __launch_bounds__(512, 2) void lstm_layer_k(
    const float* __restrict__ pre,          // [4096 rows = b*T+t][4096 gates]
    const float* __restrict__ whh,          // [4096][1024]
    const float* __restrict__ bih, const float* __restrict__ bhh,  // [4096]
    unsigned short* __restrict__ hping,     // [2][4][1024] bf16, zero-initialized
    unsigned int* __restrict__ flags,       // [32*64] u32, zero-initialized
    unsigned short* __restrict__ hseq) {    // [4096 rows = b*T+t][1024]
  int blk = blockIdx.x;                     // 0..31
  int tid = threadIdx.x;
  int wave = tid >> 6;                      // 0..7
  int lane = tid & 63;
  int n = lane & 15, quad = lane >> 4;
  int gtype = n >> 2, unit = n & 3;
  int ubase = blk * 32 + wave * 4;          // first hidden unit owned by this wave
  int grow = gtype * 1024 + ubase + unit;
  // pack W_hh b-fragments: frag[kc] elem j = W[grow][kc*32 + quad*8 + j]
  bf16x8 wf[32];
  const float* wsrc = whh + (size_t)grow * 1024 + quad * 8;
#pragma unroll
  for (int kc = 0; kc < 32; ++kc) {
    float4 f0 = *(const float4*)(wsrc + kc * 32);
    float4 f1 = *(const float4*)(wsrc + kc * 32 + 4);
    union { bf16x8 v; unsigned short s[8]; } u;
    u.s[0] = f2bf(f0.x); u.s[1] = f2bf(f0.y); u.s[2] = f2bf(f0.z); u.s[3] = f2bf(f0.w);
    u.s[4] = f2bf(f1.x); u.s[5] = f2bf(f1.y); u.s[6] = f2bf(f1.z); u.s[7] = f2bf(f1.w);
    wf[kc] = u.v;
  }
  float bias = bih[grow] + bhh[grow];
  float cst[4] = {0.f, 0.f, 0.f, 0.f};      // c state, lanes 0..3 hold unit=lane, reg=batch
  f32x4 z = {0.f, 0.f, 0.f, 0.f};
  const float* prebase = pre + grow;
  // prefetch pre for t=0
  float pf[4] = {0.f, 0.f, 0.f, 0.f};
  if (quad == 0) {
#pragma unroll
    for (int r = 0; r < 4; ++r) pf[r] = prebase[(size_t)(r * 1024) * 4096];
  }
  for (int t = 0; t < T_SEQ; ++t) {
    const unsigned short* hp = hping + (t & 1) * 4096;        // h_{t-1}
    unsigned short* hw = hping + ((t + 1) & 1) * 4096;        // h_t
    // A-fragments of h_{t-1}: m=lane&15 (batch; rows>=4 duplicate row n&3, D rows 4..15 unused)
    bf16x8 af[32];
    const unsigned short* ap = hp + (n & 3) * 1024 + quad * 8;
#pragma unroll
    for (int kc = 0; kc < 32; ++kc)
      af[kc] = *(const bf16x8*)(ap + kc * 32);
    f32x4 acc0 = z, acc1 = z, acc2 = z, acc3 = z;
    if (quad == 0) {                        // D rows m=0..3 live in quad 0, regs 0..3
#pragma unroll
      for (int r = 0; r < 4; ++r)
        acc0[r] = pf[r] + bias;
    }
#pragma unroll
    for (int kc = 0; kc < 32; kc += 4) {    // 4 independent chains to pipeline MFMA latency
      acc0 = __builtin_amdgcn_mfma_f32_16x16x32_bf16(af[kc + 0], wf[kc + 0], acc0, 0, 0, 0);
      acc1 = __builtin_amdgcn_mfma_f32_16x16x32_bf16(af[kc + 1], wf[kc + 1], acc1, 0, 0, 0);
      acc2 = __builtin_amdgcn_mfma_f32_16x16x32_bf16(af[kc + 2], wf[kc + 2], acc2, 0, 0, 0);
      acc3 = __builtin_amdgcn_mfma_f32_16x16x32_bf16(af[kc + 3], wf[kc + 3], acc3, 0, 0, 0);
    }
    f32x4 gv;
#pragma unroll
    for (int r = 0; r < 4; ++r)
      gv[r] = acc0[r] + acc1[r] + acc2[r] + acc3[r];
    // gather i/f/g/o for unit q=lane (lanes 0..3) from lanes q, q+4, q+8, q+12 (quad 0 = m 0..3)
    int src = lane & 3;
#pragma unroll
    for (int r = 0; r < 4; ++r) {
      float iv = __shfl(gv[r], src);
      float fv = __shfl(gv[r], src + 4);
      float gg = __shfl(gv[r], src + 8);
      float ov = __shfl(gv[r], src + 12);
      if (lane < 4) {
        float cn = sigm(fv) * cst[r] + sigm(iv) * tanh_f(gg);
        cst[r] = cn;
        unsigned short hb = f2bf(sigm(ov) * tanh_f(cn));
        hw[r * 1024 + ubase + lane] = hb;
        hseq[(size_t)(r * 1024 + t) * 1024 + ubase + lane] = hb;
      }
    }
    // publish h_t: per-wave fence -> block barrier -> one release store of this block's flag
    __threadfence();
    __syncthreads();
    if (tid == 0)
      __hip_atomic_store(&flags[blk * 64], (unsigned)(t + 1), __ATOMIC_RELEASE,
                         __HIP_MEMORY_SCOPE_AGENT);
    // prefetch pre for next step while waiting (independent of h)
    int tn = (t + 1) & (T_SEQ - 1);
    if (quad == 0) {
#pragma unroll
      for (int r = 0; r < 4; ++r) pf[r] = prebase[(size_t)(r * 1024 + tn) * 4096];
    }
    // wait for all 32 blocks (ping-pong makes WAR-safe); every wave acquires (L1 invalidate)
    if (t + 1 < T_SEQ) {
      unsigned tgt = (unsigned)(t + 1);
      unsigned int* fp = flags + (lane & 31) * 64;
      unsigned v = __hip_atomic_load(fp, __ATOMIC_ACQUIRE, __HIP_MEMORY_SCOPE_AGENT);
      while (__any(v < tgt)) {
        __builtin_amdgcn_s_sleep(1);
        v = __hip_atomic_load(fp, __ATOMIC_ACQUIRE, __HIP_MEMORY_SCOPE_AGENT);
      }
    }
  }
}

// ---------------- LayerNorm over H=1024, bf16 in -> bf16 out ----------------
__global__ __launch_bounds__(256) void ln_k(const unsigned short* __restrict__ x,
                                            const float* __restrict__ w,
                                            const float* __restrict__ b,
                                            unsigned short* __restrict__ y) {
  int row = blockIdx.x, tid = threadIdx.x;
  const unsigned short* xr = x + (size_t)row * 1024;
  ushort4 u = ((const ushort4*)xr)[tid];
  float v0 = bf2f(u.x), v1 = bf2f(u.y), v2 = bf2f(u.z), v3 = bf2f(u.w);
  float s = v0 + v1 + v2 + v3;
  float ss = v0 * v0 + v1 * v1 + v2 * v2 + v3 * v3;
#pragma unroll
  for (int off = 32; off > 0; off >>= 1) {
    s += __shfl_down(s, off);
    ss += __shfl_down(ss, off);
  }
  __shared__ float rs[4], rss[4];
  if ((tid & 63) == 0) { rs[tid >> 6] = s; rss[tid >> 6] = ss; }
  __syncthreads();
  s = rs[0] + rs[1] + rs[2] + rs[3];
  ss = rss[0] + rss[1] + rss[2] + rss[3];
  float mu = s * (1.f / 1024.f);
  float var = ss * (1.f / 1024.f) - mu * mu;
  float inv = rsqrtf(var + 1e-5f);
  int i4 = tid * 4;
  ushort4 o;
  o.x = f2bf((v0 - mu) * inv * w[i4 + 0] + b[i4 + 0]);
  o.y = f2bf((v1 - mu) * inv * w[i4 + 1] + b[i4 + 1]);
  o.z = f2bf((v2 - mu) * inv * w[i4 + 2] + b[i4 + 2]);
  o.w = f2bf((v3 - mu) * inv * w[i4 + 3] + b[i4 + 3]);
  ((ushort4*)(y + (size_t)row * 1024))[tid] = o;
}

extern "C" void kernel_launch(void* const* d_in, const int* in_sizes, int n_in,
                              void* d_out, int out_size, void* d_ws, size_t ws_size,
                              hipStream_t stream) {
  const int* ids = (const int*)d_in[0];
  const float* wemb = (const float*)d_in[1];
  const float* pemb = (const float*)d_in[2];
  const float* Wih = (const float*)d_in[3];
  const float* Whh = (const float*)d_in[4];
  const float* bih = (const float*)d_in[5];
  const float* bhh = (const float*)d_in[6];
  const float* lnw = (const float*)d_in[7];
  const float* lnb = (const float*)d_in[8];
  float* out = (float*)d_out;

  char* w = (char*)d_ws;
  // ws layout
  // hping: 2 layers x [2][4][1024] bf16 = 2 x 16 KB
  unsigned short* hping0 = (unsigned short*)w;
  unsigned short* hping1 = hping0 + 8192;
  // flags: 2 layers x 32 blocks x 64 u32 (256B stride) = 2 x 8 KB
  unsigned int* flags0 = (unsigned int*)(w + 32768);
  unsigned int* flags1 = flags0 + 2048;
  const size_t OFF_WIH = 262144;
  const size_t SZ_WIH = (size_t)2 * 4096 * 1024 * 2;          // 16 MB
  const size_t OFF_WEMB = OFF_WIH + SZ_WIH;
  const size_t SZ_WEMB = (size_t)32000 * 1024 * 2;            // 64 MB
  const size_t OFF_FEATS = OFF_WEMB + SZ_WEMB;
  const size_t SZ_SEQ = (size_t)4096 * 1024 * 2;              // 8 MB each
  const size_t OFF_HSEQ0 = OFF_FEATS + SZ_SEQ;
  const size_t OFF_HSEQ1 = OFF_HSEQ0 + SZ_SEQ;
  const size_t OFF_XLN = OFF_HSEQ1 + SZ_SEQ;
  const size_t OFF_PRE = OFF_XLN + SZ_SEQ;                    // 64 MB fp32; total ~175 MB
  unsigned short* wih_bf = (unsigned short*)(w + OFF_WIH);
  unsigned short* wemb_bf = (unsigned short*)(w + OFF_WEMB);
  unsigned short* feats = (unsigned short*)(w + OFF_FEATS);
  unsigned short* hseq0 = (unsigned short*)(w + OFF_HSEQ0);
  unsigned short* hseq1 = (unsigned short*)(w + OFF_HSEQ1);
  unsigned short* xln = (unsigned short*)(w + OFF_XLN);
  float* pre = (float*)(w + OFF_PRE);

  // zero h ping-pong buffers (h_0 = 0) + flag arrays
  hipMemsetAsync(d_ws, 0, 49152, stream);

  cvt_bf16<<<8192, 256, 0, stream>>>(Wih, wih_bf, 2097152);        // 2*4096*1024 / 4
  cvt_bf16<<<32000, 256, 0, stream>>>(wemb, wemb_bf, 8192000);     // 32000*1024 / 4
  embed_k<<<16384, 256, 0, stream>>>(ids, wemb, pemb, feats);

  // layer 0
  gemm_bt<<<dim3(32, 32), 256, 0, stream>>>(feats, wih_bf, pre, 4096);
  lstm_layer_k<<<32, 512, 0, stream>>>(pre, Whh, bih, bhh, hping0, flags0, hseq0);
  // layer 1
  gemm_bt<<<dim3(32, 32), 256, 0, stream>>>(hseq0, wih_bf + (size_t)4096 * 1024, pre, 4096);
  lstm_layer_k<<<32, 512, 0, stream>>>(pre, Whh + (size_t)4096 * 1024, bih + 4096, bhh + 4096,
                                       hping1, flags1, hseq1);
  // LN + tied head
  ln_k<<<4096, 256, 0, stream>>>(hseq1, lnw, lnb, xln);
  gemm_bt<<<dim3(250, 32), 256, 0, stream>>>(xln, wemb_bf, out, 32000);
}